// Round 1
// baseline (300.943 us; speedup 1.0000x reference)
//
#include <hip/hip_runtime.h>
#include <hip/hip_bf16.h>

typedef __bf16 bf16x8 __attribute__((ext_vector_type(8)));
typedef float f32x4 __attribute__((ext_vector_type(4)));

#define NB 2
#define NT 2048
#define ND 256
#define NH 8

__device__ inline __bf16 to_bf16(float f) {
  union { __hip_bfloat16 h; __bf16 b; } u;
  u.h = __float2bfloat16(f);
  return u.b;
}

// ---------------------------------------------------------------------------
// Kernel 1: convert r'->bf16 (Rb), Q -> bf16 transposed (Qt[h][j][i]), E->bf16
// ---------------------------------------------------------------------------
__global__ __launch_bounds__(256) void convert_kernel(
    const float* __restrict__ r, const float* __restrict__ Q,
    const float* __restrict__ E,
    __bf16* __restrict__ Rb, __bf16* __restrict__ Qt, __bf16* __restrict__ Eb) {
  int idx = blockIdx.x * blockDim.x + threadIdx.x;
  const int nR = NB * NT * ND;           // 1048576
  const int nQ = NH * ND * ND;           // 524288
  const int total = nR + 2 * nQ;
  for (; idx < total; idx += gridDim.x * blockDim.x) {
    if (idx < nR) {
      Rb[idx] = to_bf16(r[idx]);
    } else if (idx < nR + nQ) {
      int t = idx - nR;
      int h = t >> 16;
      int rem = t & 65535;
      int j = rem >> 8;
      int i = rem & 255;
      Qt[t] = to_bf16(Q[(h << 16) + (i << 8) + j]);   // Qt[h][j][i] = Q[h][i][j]
    } else {
      int t = idx - nR - nQ;
      Eb[t] = to_bf16(E[t]);
    }
  }
}

// ---------------------------------------------------------------------------
// Kernel 2: generic C = A @ B^T   (A: M x 256 rows, B: N x 256 rows, bf16)
// tile 64x64, 4 waves; wave w does rows [w*16, w*16+16)
// ---------------------------------------------------------------------------
__global__ __launch_bounds__(256, 4) void gemm_abt(
    const __bf16* __restrict__ Abase, const __bf16* __restrict__ Bbase,
    __bf16* __restrict__ Cbase,
    int aStrideB, int aStrideH, int bStrideB, int bStrideH,
    int cStrideZ, int cRowStride) {
  int z = blockIdx.z;
  int bb = z >> 3, h = z & 7;
  const __bf16* A = Abase + (size_t)bb * aStrideB + (size_t)h * aStrideH;
  const __bf16* B = Bbase + (size_t)bb * bStrideB + (size_t)h * bStrideH;
  __bf16* C = Cbase + (size_t)z * cStrideZ;

  int m0 = blockIdx.x * 64, n0 = blockIdx.y * 64;
  int lane = threadIdx.x & 63, w = threadIdx.x >> 6;
  int l15 = lane & 15, lg = lane >> 4;

  f32x4 acc[4] = {};
  const __bf16* arow = A + (size_t)(m0 + w * 16 + l15) * 256 + lg * 8;
  const __bf16* brow = B + (size_t)(n0 + l15) * 256 + lg * 8;

  for (int ks = 0; ks < 8; ++ks) {
    bf16x8 af = *(const bf16x8*)(arow + ks * 32);
#pragma unroll
    for (int nt = 0; nt < 4; ++nt) {
      bf16x8 bf = *(const bf16x8*)(brow + (size_t)nt * 16 * 256 + ks * 32);
      acc[nt] = __builtin_amdgcn_mfma_f32_16x16x32_bf16(af, bf, acc[nt], 0, 0, 0);
    }
  }
#pragma unroll
  for (int nt = 0; nt < 4; ++nt)
#pragma unroll
    for (int m = 0; m < 4; ++m)
      C[(size_t)(m0 + w * 16 + lg * 4 + m) * cRowStride + n0 + nt * 16 + l15] =
          to_bf16(acc[nt][m]);
}

// ---------------------------------------------------------------------------
// Kernel 3: causal "attention": for block (t_tile, h, b):
//   loop u-tiles <= t_tile: S = Am_tile @ R_u^T (mask diag), O += S @ Vt
//   accumulate O over heads into out via atomicAdd (out pre-zeroed)
// ---------------------------------------------------------------------------
__global__ __launch_bounds__(256, 2) void attn_kernel(
    const __bf16* __restrict__ Am, const __bf16* __restrict__ Rb,
    const __bf16* __restrict__ Vt, float* __restrict__ out) {
  int t_tile = gridDim.x - 1 - blockIdx.x;   // heavy tiles first
  int h = blockIdx.y, b = blockIdx.z;
  int z = b * NH + h;
  const __bf16* Amat = Am + (size_t)z * NT * ND;   // [t][j]
  const __bf16* R = Rb + (size_t)b * NT * ND;      // [u][j]
  const __bf16* V = Vt + (size_t)z * ND * NT;      // [i][u]
  float* O = out + (size_t)b * NT * ND;

  __shared__ __bf16 Rk[64][264];   // padded: 528B rows -> 2-way banks, 16B aligned
  __shared__ __bf16 Sl[64][72];    // padded: 144B rows

  int tid = threadIdx.x;
  int lane = tid & 63, w = tid >> 6;
  int l15 = lane & 15, lg = lane >> 4;
  int t0 = t_tile * 64;

  // A-fragments for this wave's S-row slab (rows t0 + w*16 + l15), held in regs
  bf16x8 af[8];
  {
    const __bf16* arow = Amat + (size_t)(t0 + w * 16 + l15) * 256 + lg * 8;
#pragma unroll
    for (int ks = 0; ks < 8; ++ks) af[ks] = *(const bf16x8*)(arow + ks * 32);
  }

  f32x4 acc[4][4] = {};   // O tile: [t m-tile][i n-tile], wave owns i-slice w*64..+64

  for (int ut = 0; ut <= t_tile; ++ut) {
    int u0 = ut * 64;
    // stage R rows u0..u0+63 (256 j each) into LDS
    {
      int row = tid >> 2;
      int cg = tid & 3;
      const __bf16* src = R + (size_t)(u0 + row) * 256 + cg * 8;
#pragma unroll
      for (int c = 0; c < 8; ++c)
        *(bf16x8*)(&Rk[row][cg * 8 + c * 32]) = *(const bf16x8*)(src + c * 32);
    }
    __syncthreads();

    // S = A @ R^T for this wave's 16-row slab; mask; write bf16 S to LDS
#pragma unroll
    for (int nt = 0; nt < 4; ++nt) {
      f32x4 s = {};
#pragma unroll
      for (int ks = 0; ks < 8; ++ks) {
        bf16x8 bf = *(const bf16x8*)(&Rk[nt * 16 + l15][ks * 32 + lg * 8]);
        s = __builtin_amdgcn_mfma_f32_16x16x32_bf16(af[ks], bf, s, 0, 0, 0);
      }
      int ug = u0 + nt * 16 + l15;
#pragma unroll
      for (int m = 0; m < 4; ++m) {
        int tg = t0 + w * 16 + lg * 4 + m;
        float v = (ug <= tg) ? s[m] : 0.0f;   // causal (tril incl diagonal)
        Sl[w * 16 + lg * 4 + m][nt * 16 + l15] = to_bf16(v);
      }
    }
    __syncthreads();

    // O += S @ Vt   (wave w: all 64 t-rows, i-slice [w*64, w*64+64))
#pragma unroll
    for (int kt = 0; kt < 2; ++kt) {
      bf16x8 sf[4], vf[4];
#pragma unroll
      for (int mt = 0; mt < 4; ++mt)
        sf[mt] = *(const bf16x8*)(&Sl[mt * 16 + l15][kt * 32 + lg * 8]);
#pragma unroll
      for (int nt = 0; nt < 4; ++nt) {
        const __bf16* vrow =
            V + (size_t)(w * 64 + nt * 16 + l15) * NT + u0 + kt * 32 + lg * 8;
        vf[nt] = *(const bf16x8*)vrow;
      }
#pragma unroll
      for (int mt = 0; mt < 4; ++mt)
#pragma unroll
        for (int nt = 0; nt < 4; ++nt)
          acc[mt][nt] =
              __builtin_amdgcn_mfma_f32_16x16x32_bf16(sf[mt], vf[nt], acc[mt][nt], 0, 0, 0);
    }
    __syncthreads();
  }

  // epilogue: accumulate over heads
#pragma unroll
  for (int mt = 0; mt < 4; ++mt)
#pragma unroll
    for (int nt = 0; nt < 4; ++nt)
#pragma unroll
      for (int m = 0; m < 4; ++m) {
        int tg = t0 + mt * 16 + lg * 4 + m;
        int ig = w * 64 + nt * 16 + l15;
        atomicAdd(&O[(size_t)tg * ND + ig], acc[mt][nt][m]);
      }
}

// ---------------------------------------------------------------------------
extern "C" void kernel_launch(void* const* d_in, const int* in_sizes, int n_in,
                              void* d_out, int out_size, void* d_ws, size_t ws_size,
                              hipStream_t stream) {
  const float* r = (const float*)d_in[0];
  const float* Q = (const float*)d_in[1];
  const float* E = (const float*)d_in[2];
  float* out = (float*)d_out;

  char* ws = (char*)d_ws;
  __bf16* Rb = (__bf16*)(ws);                      // 2 MB  [b][t][i]
  __bf16* Qt = (__bf16*)(ws + (2u << 20));         // 1 MB  [h][j][i]
  __bf16* Eb = (__bf16*)(ws + (3u << 20));         // 1 MB  [h][i][j]
  __bf16* Am = (__bf16*)(ws + (4u << 20));         // 16 MB [b][h][t][j]
  __bf16* Vt = (__bf16*)(ws + (20u << 20));        // 16 MB [b][h][i][u]

  hipMemsetAsync(d_out, 0, (size_t)out_size * sizeof(float), stream);

  convert_kernel<<<1024, 256, 0, stream>>>(r, Q, E, Rb, Qt, Eb);

  // Am[b,h] = Rb[b] (2048x256) @ Qt[h]^T (256x256)
  gemm_abt<<<dim3(32, 4, 16), 256, 0, stream>>>(
      Rb, Qt, Am, NT * ND, 0, 0, ND * ND, NT * ND, ND);

  // Vt[b,h] = Eb[h] (256x256) @ Rb[b]^T (2048x256)^T  -> [i][u], row stride NT
  gemm_abt<<<dim3(4, 32, 16), 256, 0, stream>>>(
      Eb, Rb, Vt, 0, ND * ND, NT * ND, 0, ND * NT, NT);

  attn_kernel<<<dim3(32, NH, NB), 256, 0, stream>>>(Am, Rb, Vt, out);
}

// Round 3
// 185.809 us; speedup vs baseline: 1.6196x; 1.6196x over previous
//
#include <hip/hip_runtime.h>
#include <hip/hip_bf16.h>

typedef __bf16 bf16x8 __attribute__((ext_vector_type(8)));
typedef float f32x4 __attribute__((ext_vector_type(4)));

#define NB 2
#define NT 2048
#define ND 256
#define NH 8

__device__ inline __bf16 to_bf16(float f) {
  union { __hip_bfloat16 h; __bf16 b; } u;
  u.h = __float2bfloat16(f);
  return u.b;
}

typedef __attribute__((address_space(1))) const void g1void;
typedef __attribute__((address_space(3))) void l3void;

__device__ inline void gl_lds16(const void* g, void* l) {
  __builtin_amdgcn_global_load_lds((g1void*)g, (l3void*)l, 16, 0, 0);
}

// Stage 64 rows x 256 cols bf16 (32KB) from gsrc (row stride 256) into linear
// LDS with XOR-swizzled content: LDS chunk (row, c) holds global chunk
// (row, c ^ (row&7)).  chunk = 16B = 8 bf16.
__device__ inline void stage_tile64(const __bf16* gsrc, __bf16* lds, int tid) {
  int c = tid & 31;
  int rp = tid >> 5;  // 0..7
  const char* wave_uniform_base = (const char*)lds + (tid & ~63) * 16;
#pragma unroll
  for (int p = 0; p < 8; ++p) {
    int row = p * 8 + rp;
    const __bf16* g = gsrc + row * 256 + ((c ^ (row & 7)) << 3);
    gl_lds16((const void*)g, (void*)(wave_uniform_base + p * 4096));
  }
}

// ---------------------------------------------------------------------------
// Kernel 1: convert r'->bf16 (Rb), Q -> bf16 transposed (Qt[h][j][i]), E->bf16
// ---------------------------------------------------------------------------
__global__ __launch_bounds__(256) void convert_kernel(
    const float* __restrict__ r, const float* __restrict__ Q,
    const float* __restrict__ E,
    __bf16* __restrict__ Rb, __bf16* __restrict__ Qt, __bf16* __restrict__ Eb) {
  int idx = blockIdx.x * blockDim.x + threadIdx.x;
  const int nR = NB * NT * ND;
  const int nQ = NH * ND * ND;
  const int total = nR + 2 * nQ;
  for (; idx < total; idx += gridDim.x * blockDim.x) {
    if (idx < nR) {
      Rb[idx] = to_bf16(r[idx]);
    } else if (idx < nR + nQ) {
      int t = idx - nR;
      int h = t >> 16;
      int rem = t & 65535;
      int j = rem >> 8;
      int i = rem & 255;
      Qt[t] = to_bf16(Q[(h << 16) + (i << 8) + j]);
    } else {
      int t = idx - nR - nQ;
      Eb[t] = to_bf16(E[t]);
    }
  }
}

// ---------------------------------------------------------------------------
// Kernel 2: C = A @ B^T  (A rows x 256, B rows x 256), 64x64 tile, 4 waves.
// B-tile staged in LDS (swizzled) via global_load_lds; A-frags in registers.
// ---------------------------------------------------------------------------
__global__ __launch_bounds__(256, 4) void gemm_abt(
    const __bf16* __restrict__ Abase, const __bf16* __restrict__ Bbase,
    __bf16* __restrict__ Cbase,
    int aStrideB, int aStrideH, int bStrideB, int bStrideH,
    int cStrideZ, int cRowStride) {
  __shared__ __bf16 Bs[64 * 256];

  int z = blockIdx.z;
  int bb = z >> 3, h = z & 7;
  const __bf16* A = Abase + (size_t)bb * aStrideB + (size_t)h * aStrideH;
  const __bf16* B = Bbase + (size_t)bb * bStrideB + (size_t)h * bStrideH;
  __bf16* C = Cbase + (size_t)z * cStrideZ;

  int m0 = blockIdx.x * 64, n0 = blockIdx.y * 64;
  int tid = threadIdx.x;
  int lane = tid & 63, w = tid >> 6;
  int l15 = lane & 15, lg = lane >> 4;
  int x7 = l15 & 7;

  stage_tile64(B + (size_t)n0 * 256, Bs, tid);

  bf16x8 af[8];
  const __bf16* arow = A + (size_t)(m0 + w * 16 + l15) * 256 + lg * 8;
#pragma unroll
  for (int ks = 0; ks < 8; ++ks) af[ks] = *(const bf16x8*)(arow + ks * 32);

  __syncthreads();  // drains vmcnt: B-tile staged, af in regs

  f32x4 acc[4] = {};
#pragma unroll
  for (int ks = 0; ks < 8; ++ks) {
#pragma unroll
    for (int nt = 0; nt < 4; ++nt) {
      int row = nt * 16 + l15;
      int ch = (ks * 4 + lg) ^ x7;
      bf16x8 bfr = *(const bf16x8*)(&Bs[row * 256 + ch * 8]);
      acc[nt] = __builtin_amdgcn_mfma_f32_16x16x32_bf16(af[ks], bfr, acc[nt], 0, 0, 0);
    }
  }
#pragma unroll
  for (int nt = 0; nt < 4; ++nt)
#pragma unroll
    for (int m = 0; m < 4; ++m)
      C[(size_t)(m0 + w * 16 + lg * 4 + m) * cRowStride + n0 + nt * 16 + l15] =
          to_bf16(acc[nt][m]);
}

// ---------------------------------------------------------------------------
// Kernel 3: causal attention-like. Block x = (pair,parity): processes t_tile
// p then 31-p, u-tiles of its parity -> ~16.5 iterations per block (balanced).
// Double-buffered swizzled R-tile via global_load_lds; 2 barriers/iter.
// ---------------------------------------------------------------------------
__global__ __launch_bounds__(256, 2) void attn_kernel(
    const __bf16* __restrict__ Am, const __bf16* __restrict__ Rb,
    const __bf16* __restrict__ Vt, float* __restrict__ out) {
  __shared__ __bf16 Rk[2][64 * 256];  // 64KB, swizzled content
  __shared__ __bf16 Sl[64][72];       // 9KB, padded

  int px = blockIdx.x >> 1;  // pair 0..15
  int q = blockIdx.x & 1;    // parity
  int h = blockIdx.y, b = blockIdx.z;
  int z = b * NH + h;
  const __bf16* Amat = Am + (size_t)z * NT * ND;
  const __bf16* R = Rb + (size_t)b * NT * ND;
  const __bf16* V = Vt + (size_t)z * ND * NT;
  float* O = out + (size_t)b * NT * ND;

  int tid = threadIdx.x;
  int lane = tid & 63, w = tid >> 6;
  int l15 = lane & 15, lg = lane >> 4;
  int x7 = l15 & 7;

#pragma unroll 1
  for (int half = 0; half < 2; ++half) {
    int tt = half ? (31 - px) : px;
    int t0 = tt * 64;

    // A-fragments for this wave's 16-row slab
    bf16x8 af[8];
    {
      const __bf16* arow = Amat + (size_t)(t0 + w * 16 + l15) * 256 + lg * 8;
#pragma unroll
      for (int ks = 0; ks < 8; ++ks) af[ks] = *(const bf16x8*)(arow + ks * 32);
    }

    f32x4 acc[4][4] = {};

    if (tt >= q) {
      // prologue: stage first u-tile into buf 0
      stage_tile64(R + (size_t)q * 64 * 256, &Rk[0][0], tid);
      asm volatile("s_waitcnt vmcnt(0)" ::: "memory");
      __builtin_amdgcn_s_barrier();

      int buf = 0;
#pragma unroll 1
      for (int ut = q; ut <= tt; ut += 2) {
        int u0 = ut * 64;
        // issue next-tile staging (overlaps S-GEMM + O-GEMM)
        if (ut + 2 <= tt)
          stage_tile64(R + (size_t)(ut + 2) * 64 * 256, &Rk[buf ^ 1][0], tid);

        // S = A @ R^T (this wave's 16 t-rows), mask, write bf16 to Sl
        const __bf16* Rcur = &Rk[buf][0];
#pragma unroll
        for (int nt = 0; nt < 4; ++nt) {
          f32x4 s = {};
          int row = nt * 16 + l15;
#pragma unroll
          for (int ks = 0; ks < 8; ++ks) {
            int ch = (ks * 4 + lg) ^ x7;
            bf16x8 bfr = *(const bf16x8*)(Rcur + row * 256 + ch * 8);
            s = __builtin_amdgcn_mfma_f32_16x16x32_bf16(af[ks], bfr, s, 0, 0, 0);
          }
          int ug = u0 + nt * 16 + l15;
#pragma unroll
          for (int m = 0; m < 4; ++m) {
            int tg = t0 + w * 16 + lg * 4 + m;
            float v = (ug <= tg) ? s[m] : 0.0f;
            Sl[w * 16 + lg * 4 + m][nt * 16 + l15] = to_bf16(v);
          }
        }
        // barrier 1: Sl visible; do NOT drain vmcnt (staging stays in flight)
        asm volatile("s_waitcnt lgkmcnt(0)" ::: "memory");
        __builtin_amdgcn_s_barrier();

        // O += S @ Vt  (wave w owns i-slice [w*64, w*64+64))
#pragma unroll
        for (int kt = 0; kt < 2; ++kt) {
          bf16x8 sf[4], vf[4];
#pragma unroll
          for (int mt = 0; mt < 4; ++mt)
            sf[mt] = *(const bf16x8*)(&Sl[mt * 16 + l15][kt * 32 + lg * 8]);
#pragma unroll
          for (int nt = 0; nt < 4; ++nt) {
            const __bf16* vrow =
                V + (size_t)(w * 64 + nt * 16 + l15) * NT + u0 + kt * 32 + lg * 8;
            vf[nt] = *(const bf16x8*)vrow;
          }
#pragma unroll
          for (int mt = 0; mt < 4; ++mt)
#pragma unroll
            for (int nt = 0; nt < 4; ++nt)
              acc[mt][nt] = __builtin_amdgcn_mfma_f32_16x16x32_bf16(
                  sf[mt], vf[nt], acc[mt][nt], 0, 0, 0);
        }
        // barrier 2: full drain (next tile staged + Sl consumed)
        asm volatile("s_waitcnt vmcnt(0) lgkmcnt(0)" ::: "memory");
        __builtin_amdgcn_s_barrier();
        buf ^= 1;
      }
    }

    // epilogue: accumulate over (h, parity) into out
#pragma unroll
    for (int mt = 0; mt < 4; ++mt)
#pragma unroll
      for (int nt = 0; nt < 4; ++nt)
#pragma unroll
        for (int m = 0; m < 4; ++m) {
          int tg = t0 + mt * 16 + lg * 4 + m;
          int ig = w * 64 + nt * 16 + l15;
          atomicAdd(&O[(size_t)tg * ND + ig], acc[mt][nt][m]);
        }
  }
}

// ---------------------------------------------------------------------------
extern "C" void kernel_launch(void* const* d_in, const int* in_sizes, int n_in,
                              void* d_out, int out_size, void* d_ws, size_t ws_size,
                              hipStream_t stream) {
  const float* r = (const float*)d_in[0];
  const float* Q = (const float*)d_in[1];
  const float* E = (const float*)d_in[2];
  float* out = (float*)d_out;

  char* ws = (char*)d_ws;
  __bf16* Rb = (__bf16*)(ws);                // 2 MB  [b][t][i]
  __bf16* Qt = (__bf16*)(ws + (2u << 20));   // 1 MB  [h][j][i]
  __bf16* Eb = (__bf16*)(ws + (3u << 20));   // 1 MB  [h][i][j]
  __bf16* Am = (__bf16*)(ws + (4u << 20));   // 16 MB [b][h][t][j]
  __bf16* Vt = (__bf16*)(ws + (20u << 20));  // 16 MB [b][h][i][u]

  hipMemsetAsync(d_out, 0, (size_t)out_size * sizeof(float), stream);

  convert_kernel<<<1024, 256, 0, stream>>>(r, Q, E, Rb, Qt, Eb);

  // Am[b,h] = Rb[b] (2048x256) @ Qt[h]^T
  gemm_abt<<<dim3(32, 4, 16), 256, 0, stream>>>(
      Rb, Qt, Am, NT * ND, 0, 0, ND * ND, NT * ND, ND);

  // Vt[b,h] = (Eb[h] @ Rb[b]^T) -> [i][u], row stride NT
  gemm_abt<<<dim3(4, 32, 16), 256, 0, stream>>>(
      Eb, Rb, Vt, 0, ND * ND, NT * ND, 0, ND * NT, NT);

  attn_kernel<<<dim3(32, NH, NB), 256, 0, stream>>>(Am, Rb, Vt, out);
}